// Round 1
// baseline (179.850 us; speedup 1.0000x reference)
//
#include <hip/hip_runtime.h>

// SymmetricChannel: B=1024, L=32, V=1024; BL = 32768 rows.
// Outputs (concat, each BL*V f32): noisy_messages, noisy_probs, messages, probs.
//
// Per row r, tail col j in [1,V):
//   T[j]   = msg[j] * mask[r][j-1]
//   sum    = sum_j T[j]
//   noisyM = msg[j] + sum/(V-2) - T[j]*(1 + 1/(V-2))
//   noisyP = p[j]*(1-P) + (1 - p[j] - p[0]) * P/(V-2)
// Col 0 passes through unchanged.

constexpr int V   = 1024;
constexpr int VM1 = V - 1;

__global__ __launch_bounds__(256)
void symchan_kernel(const float* __restrict__ msgs,
                    const float* __restrict__ probs,
                    const int*   __restrict__ mask,
                    float*       __restrict__ out,
                    long long N)           // N = BL*V (elements per output)
{
    const int r = blockIdx.x;
    const int t = threadIdx.x;          // 256 threads, 4 cols each
    const long long rowBase = (long long)r * V;
    const long long idx = rowBase + 4LL * t;

    const float4 mv = *reinterpret_cast<const float4*>(msgs  + idx);
    const float4 pv = *reinterpret_cast<const float4*>(probs + idx);

    // mask row: VM1 ints, col j maps to mask[j-1]
    const int* mk = mask + (long long)r * VM1;
    const int j0 = t << 2;
    const float m0 = (t == 0) ? 0.0f : (mk[j0 - 1] ? 1.0f : 0.0f);
    const float m1 = mk[j0 + 0] ? 1.0f : 0.0f;
    const float m2 = mk[j0 + 1] ? 1.0f : 0.0f;
    const float m3 = mk[j0 + 2] ? 1.0f : 0.0f;

    const float T0 = mv.x * m0;
    const float T1 = mv.y * m1;
    const float T2 = mv.z * m2;
    const float T3 = mv.w * m3;

    // block-wide row_sum: wave64 shuffle reduce, then 4-slot LDS combine
    float partial = (T0 + T1) + (T2 + T3);
    #pragma unroll
    for (int off = 32; off > 0; off >>= 1)
        partial += __shfl_down(partial, off, 64);

    __shared__ float wsum[4];
    __shared__ float p0s;
    const int lane = t & 63;
    const int wid  = t >> 6;
    if (lane == 0) wsum[wid] = partial;
    if (t == 0)    p0s = pv.x;          // probs col 0 for this row
    __syncthreads();
    const float row_sum = (wsum[0] + wsum[1]) + (wsum[2] + wsum[3]);
    const float p0 = p0s;

    constexpr float inv = 1.0f / (float)(V - 2);
    constexpr float P   = 0.1f;
    const float add = row_sum * inv;
    const float c1  = 1.0f + inv;

    float4 nm;
    nm.x = (t == 0) ? mv.x : mv.x + add - T0 * c1;
    nm.y = mv.y + add - T1 * c1;
    nm.z = mv.z + add - T2 * c1;
    nm.w = mv.w + add - T3 * c1;

    const float q  = 1.0f - P;
    const float pc = P * inv;
    float4 npv;
    npv.x = (t == 0) ? pv.x : pv.x * q + (1.0f - pv.x - p0) * pc;
    npv.y = pv.y * q + (1.0f - pv.y - p0) * pc;
    npv.z = pv.z * q + (1.0f - pv.z - p0) * pc;
    npv.w = pv.w * q + (1.0f - pv.w - p0) * pc;

    *reinterpret_cast<float4*>(out + idx)            = nm;
    *reinterpret_cast<float4*>(out + N + idx)        = npv;
    *reinterpret_cast<float4*>(out + 2 * N + idx)    = mv;
    *reinterpret_cast<float4*>(out + 3 * N + idx)    = pv;
}

extern "C" void kernel_launch(void* const* d_in, const int* in_sizes, int n_in,
                              void* d_out, int out_size, void* d_ws, size_t ws_size,
                              hipStream_t stream) {
    const float* msgs  = (const float*)d_in[0];
    const float* probs = (const float*)d_in[1];
    const int*   mask  = (const int*)d_in[2];
    float* out = (float*)d_out;

    const long long N  = (long long)in_sizes[0];   // BL*V
    const int       BL = (int)(N / V);

    symchan_kernel<<<BL, 256, 0, stream>>>(msgs, probs, mask, out, N);
}

// Round 2
// 149.651 us; speedup vs baseline: 1.2018x; 1.2018x over previous
//
#include <hip/hip_runtime.h>

// SymmetricChannel: B=1024, L=32, V=1024; BL = 32768 rows.
// Outputs (concat, each BL*V f32): noisy_messages, noisy_probs, messages, probs.
//
// Wave-per-row layout: 64 lanes x 16 cols (4 interleaved float4 chunks at
// col = 256*c + 4*lane). Row-sum via 6-step shfl_xor butterfly; no LDS, no
// barriers. Streaming data uses nontemporal loads/stores; mask keeps cached
// loads (its 4 strided dword loads per chunk rely on L1 line reuse).

constexpr int V   = 1024;
constexpr int VM1 = V - 1;

typedef float f4 __attribute__((ext_vector_type(4)));

__global__ __launch_bounds__(256)
void symchan_kernel(const float* __restrict__ msgs,
                    const float* __restrict__ probs,
                    const int*   __restrict__ mask,
                    float*       __restrict__ out,
                    long long N)           // N = BL*V (elements per output)
{
    const int wid  = threadIdx.x >> 6;
    const int lane = threadIdx.x & 63;
    const long long row = (long long)blockIdx.x * 4 + wid;
    const long long rowBase = row * V;
    const int* mk = mask + row * (long long)VM1;

    f4 mv[4], pv[4];
    float T[4][4];

    #pragma unroll
    for (int c = 0; c < 4; ++c) {
        const int j0 = 256 * c + 4 * lane;
        mv[c] = __builtin_nontemporal_load(
                    reinterpret_cast<const f4*>(msgs + rowBase + j0));
        pv[c] = __builtin_nontemporal_load(
                    reinterpret_cast<const f4*>(probs + rowBase + j0));
    }

    #pragma unroll
    for (int c = 0; c < 4; ++c) {
        const int j0 = 256 * c + 4 * lane;
        const float m0 = (j0 == 0) ? 0.0f : (mk[j0 - 1] ? 1.0f : 0.0f);
        const float m1 = mk[j0 + 0] ? 1.0f : 0.0f;
        const float m2 = mk[j0 + 1] ? 1.0f : 0.0f;
        const float m3 = mk[j0 + 2] ? 1.0f : 0.0f;
        T[c][0] = mv[c].x * m0;
        T[c][1] = mv[c].y * m1;
        T[c][2] = mv[c].z * m2;
        T[c][3] = mv[c].w * m3;
    }

    float partial = 0.0f;
    #pragma unroll
    for (int c = 0; c < 4; ++c)
        partial += (T[c][0] + T[c][1]) + (T[c][2] + T[c][3]);

    // butterfly: every lane ends with the full row sum
    #pragma unroll
    for (int m = 1; m < 64; m <<= 1)
        partial += __shfl_xor(partial, m, 64);
    const float row_sum = partial;

    const float p0 = __shfl(pv[0].x, 0, 64);   // probs col 0 of this row

    constexpr float inv = 1.0f / (float)(V - 2);
    constexpr float P   = 0.1f;
    const float add = row_sum * inv;
    const float c1  = 1.0f + inv;
    const float q   = 1.0f - P;
    const float pc  = P * inv;

    #pragma unroll
    for (int c = 0; c < 4; ++c) {
        const int j0 = 256 * c + 4 * lane;
        const long long idx = rowBase + j0;
        const bool col0 = (j0 == 0);

        f4 nm;
        nm.x = col0 ? mv[c].x : mv[c].x + add - T[c][0] * c1;
        nm.y = mv[c].y + add - T[c][1] * c1;
        nm.z = mv[c].z + add - T[c][2] * c1;
        nm.w = mv[c].w + add - T[c][3] * c1;

        f4 np;
        np.x = col0 ? pv[c].x : pv[c].x * q + (1.0f - pv[c].x - p0) * pc;
        np.y = pv[c].y * q + (1.0f - pv[c].y - p0) * pc;
        np.z = pv[c].z * q + (1.0f - pv[c].z - p0) * pc;
        np.w = pv[c].w * q + (1.0f - pv[c].w - p0) * pc;

        __builtin_nontemporal_store(nm,    reinterpret_cast<f4*>(out + idx));
        __builtin_nontemporal_store(np,    reinterpret_cast<f4*>(out + N + idx));
        __builtin_nontemporal_store(mv[c], reinterpret_cast<f4*>(out + 2 * N + idx));
        __builtin_nontemporal_store(pv[c], reinterpret_cast<f4*>(out + 3 * N + idx));
    }
}

extern "C" void kernel_launch(void* const* d_in, const int* in_sizes, int n_in,
                              void* d_out, int out_size, void* d_ws, size_t ws_size,
                              hipStream_t stream) {
    const float* msgs  = (const float*)d_in[0];
    const float* probs = (const float*)d_in[1];
    const int*   mask  = (const int*)d_in[2];
    float* out = (float*)d_out;

    const long long N  = (long long)in_sizes[0];   // BL*V
    const int       BL = (int)(N / V);              // 32768 rows
    const int       nb = BL / 4;                    // 4 rows (waves) per block

    symchan_kernel<<<nb, 256, 0, stream>>>(msgs, probs, mask, out, N);
}